// Round 2
// baseline (3628.807 us; speedup 1.0000x reference)
//
#include <hip/hip_runtime.h>
#include <math.h>

#define NA      128
#define NBATCH  2048
#define NIT     300
#define NBIS    40
#define LRC     0.02f
#define EPSC    1e-8f

// ---- wave64 cross-lane reductions via DPP (VALU pipe, no LDS traffic) ----
// row_shr:n = 0x110+n ; row_bcast:15 = 0x142 ; row_bcast:31 = 0x143
// dpp_ctrl must be an ICE at the builtin call site -> template parameter.
template <int CTRL>
__device__ __forceinline__ float dpp_sum_step(float x) {
  int s = __builtin_amdgcn_update_dpp(0, __float_as_int(x), CTRL, 0xF, 0xF, true);
  return x + __int_as_float(s);
}
__device__ __forceinline__ float wave_sum64(float x) {
  x = dpp_sum_step<0x111>(x);
  x = dpp_sum_step<0x112>(x);
  x = dpp_sum_step<0x114>(x);
  x = dpp_sum_step<0x118>(x);
  x = dpp_sum_step<0x142>(x);
  x = dpp_sum_step<0x143>(x);
  return x;  // full-wave total lands in lane 63
}
template <int CTRL>
__device__ __forceinline__ float dpp_mov_self(float x) {
  // invalid/unwritten lanes keep old = x (identity for min/max)
  int s = __builtin_amdgcn_update_dpp(__float_as_int(x), __float_as_int(x), CTRL, 0xF, 0xF, false);
  return __int_as_float(s);
}
__device__ __forceinline__ float wave_min64(float x) {
  x = fminf(x, dpp_mov_self<0x111>(x));
  x = fminf(x, dpp_mov_self<0x112>(x));
  x = fminf(x, dpp_mov_self<0x114>(x));
  x = fminf(x, dpp_mov_self<0x118>(x));
  x = fminf(x, dpp_mov_self<0x142>(x));
  x = fminf(x, dpp_mov_self<0x143>(x));
  return x;  // min in lane 63
}
__device__ __forceinline__ float wave_max64(float x) {
  x = fmaxf(x, dpp_mov_self<0x111>(x));
  x = fmaxf(x, dpp_mov_self<0x112>(x));
  x = fmaxf(x, dpp_mov_self<0x114>(x));
  x = fmaxf(x, dpp_mov_self<0x118>(x));
  x = fmaxf(x, dpp_mov_self<0x142>(x));
  x = fmaxf(x, dpp_mov_self<0x143>(x));
  return x;  // max in lane 63
}
__device__ __forceinline__ float read_lane63(float x) {
  return __int_as_float(__builtin_amdgcn_readlane(__float_as_int(x), 63));
}
__device__ __forceinline__ float clip1(float x) {
  return __builtin_amdgcn_fmed3f(x, -1.0f, 1.0f);  // clip to [-c, c], c = MAX_WEIGHT = 1
}

// One block per batch element. 128 threads: thread t owns asset t.
// A-row (gamma-folded) lives in 128 VGPRs per thread; w is broadcast from LDS.
__global__ __launch_bounds__(NA) void markowitz_kernel(
    const float* __restrict__ rets,
    const float* __restrict__ covmat,
    const float* __restrict__ gamma,
    const float* __restrict__ alpha,
    float* __restrict__ out)
{
  const int b    = blockIdx.x;
  const int t    = threadIdx.x;
  const int lane = t & 63;
  const int wv   = t >> 6;  // wave 0 or 1

  __shared__ __align__(16) float ws[NA];   // current weights
  __shared__ __align__(16) float vs[NA];   // pre-projection vector for bisection
  __shared__ float pp[8];                  // [0..3]: w·Aw, w·w per wave; [4,5]: min; [6,7]: max
  __shared__ float tau_s;

  // ---- one-time load: A row t with gamma folded in (A = gamma * covmat) ----
  const float gm = gamma[b];
  const float4* Arow = reinterpret_cast<const float4*>(
      covmat + (size_t)b * NA * NA + (size_t)t * NA);
  float4 a[32];
#pragma unroll
  for (int k = 0; k < 32; ++k) {
    float4 q = Arow[k];
    a[k] = make_float4(q.x * gm, q.y * gm, q.z * gm, q.w * gm);
  }
  const float r_t = rets[b * NA + t];
  const float av  = fabsf(alpha[b]);

  float w_t = 1.0f / NA;
  ws[t] = w_t;
  __syncthreads();

#pragma unroll 1
  for (int it = 0; it < NIT; ++it) {
    // ---- 1. Aw[t] = A[t,:] · w  (A in regs, w broadcast from LDS) ----
    const float4* ws4 = reinterpret_cast<const float4*>(ws);
    float4 acc = make_float4(0.f, 0.f, 0.f, 0.f);
#pragma unroll
    for (int k = 0; k < 32; ++k) {
      float4 wk = ws4[k];  // uniform address -> single broadcast ds_read_b128
      acc.x = fmaf(a[k].x, wk.x, acc.x);
      acc.y = fmaf(a[k].y, wk.y, acc.y);
      acc.z = fmaf(a[k].z, wk.z, acc.z);
      acc.w = fmaf(a[k].w, wk.w, acc.w);
    }
    const float Aw = (acc.x + acc.y) + (acc.z + acc.w);

    // ---- 2. risk = sqrt(w·Aw + eps), nrm = sqrt(w·w + eps) ----
    float p1 = wave_sum64(w_t * Aw);
    float p2 = wave_sum64(w_t * w_t);
    if (lane == 63) { pp[wv * 2 + 0] = p1; pp[wv * 2 + 1] = p2; }
    __syncthreads();
    const float risk = sqrtf(pp[0] + pp[2] + EPSC);
    const float nrm  = sqrtf(pp[1] + pp[3] + EPSC);

    // ---- 3. gradient ascent step ----
    const float g_t = r_t - Aw / risk - av * (w_t / nrm);
    const float v_t = w_t + LRC * g_t;
    vs[t] = v_t;
    float mn = wave_min64(v_t);
    float mx = wave_max64(v_t);
    if (lane == 63) { pp[4 + wv] = mn; pp[6 + wv] = mx; }
    __syncthreads();

    // ---- 4. bisection for tau (wave 0 only; 2 elements per lane) ----
    if (wv == 0) {
      float v0 = vs[lane];
      float v1 = vs[lane + 64];
      float lo = fminf(pp[4], pp[5]) - 2.0f;  // min(v) - c - 1
      float hi = fmaxf(pp[6], pp[7]) + 1.0f;  // max(v) + c
#pragma unroll 1
      for (int r = 0; r < NBIS; ++r) {
        const float mid = 0.5f * (lo + hi);
        float s = clip1(v0 - mid) + clip1(v1 - mid);
        s = wave_sum64(s);
        const float stot = read_lane63(s);
        const bool big = stot > 1.0f;
        lo = big ? mid : lo;
        hi = big ? hi : mid;
      }
      if (lane == 0) tau_s = 0.5f * (lo + hi);
    }
    __syncthreads();

    // ---- 5. project: w = clip(v - tau, -c, c) ----
    const float tau = tau_s;
    w_t = clip1(v_t - tau);
    ws[t] = w_t;
    __syncthreads();
  }

  out[b * NA + t] = w_t;
}

extern "C" void kernel_launch(void* const* d_in, const int* in_sizes, int n_in,
                              void* d_out, int out_size, void* d_ws, size_t ws_size,
                              hipStream_t stream) {
  const float* rets   = (const float*)d_in[0];
  const float* covmat = (const float*)d_in[1];
  const float* gamma  = (const float*)d_in[2];
  const float* alpha  = (const float*)d_in[3];
  float* out = (float*)d_out;

  hipLaunchKernelGGL(markowitz_kernel, dim3(NBATCH), dim3(NA), 0, stream,
                     rets, covmat, gamma, alpha, out);
}

// Round 3
// 3625.080 us; speedup vs baseline: 1.0010x; 1.0010x over previous
//
#include <hip/hip_runtime.h>
#include <math.h>

#define NA      128
#define NBATCH  2048
#define NIT     300
#define NBIS    40
#define LRC     0.02f
#define EPSC    1e-8f

// ---- wave64 cross-lane reductions via DPP (VALU pipe, no LDS traffic) ----
// row_shr:n = 0x110+n ; row_bcast:15 = 0x142 ; row_bcast:31 = 0x143
// dpp_ctrl must be an ICE at the builtin call site -> template parameter.
template <int CTRL>
__device__ __forceinline__ float dpp_sum_step(float x) {
  int s = __builtin_amdgcn_update_dpp(0, __float_as_int(x), CTRL, 0xF, 0xF, true);
  return x + __int_as_float(s);
}
__device__ __forceinline__ float wave_sum64(float x) {
  x = dpp_sum_step<0x111>(x);
  x = dpp_sum_step<0x112>(x);
  x = dpp_sum_step<0x114>(x);
  x = dpp_sum_step<0x118>(x);
  x = dpp_sum_step<0x142>(x);
  x = dpp_sum_step<0x143>(x);
  return x;  // full-wave total lands in lane 63
}
template <int CTRL>
__device__ __forceinline__ float dpp_mov_self(float x) {
  // invalid/unwritten lanes keep old = x (identity for min/max)
  int s = __builtin_amdgcn_update_dpp(__float_as_int(x), __float_as_int(x), CTRL, 0xF, 0xF, false);
  return __int_as_float(s);
}
__device__ __forceinline__ float wave_min64(float x) {
  x = fminf(x, dpp_mov_self<0x111>(x));
  x = fminf(x, dpp_mov_self<0x112>(x));
  x = fminf(x, dpp_mov_self<0x114>(x));
  x = fminf(x, dpp_mov_self<0x118>(x));
  x = fminf(x, dpp_mov_self<0x142>(x));
  x = fminf(x, dpp_mov_self<0x143>(x));
  return x;  // min in lane 63
}
__device__ __forceinline__ float wave_max64(float x) {
  x = fmaxf(x, dpp_mov_self<0x111>(x));
  x = fmaxf(x, dpp_mov_self<0x112>(x));
  x = fmaxf(x, dpp_mov_self<0x114>(x));
  x = fmaxf(x, dpp_mov_self<0x118>(x));
  x = fmaxf(x, dpp_mov_self<0x142>(x));
  x = fmaxf(x, dpp_mov_self<0x143>(x));
  return x;  // max in lane 63
}
__device__ __forceinline__ float read_lane63(float x) {
  return __int_as_float(__builtin_amdgcn_readlane(__float_as_int(x), 63));
}
__device__ __forceinline__ float clip1(float x) {
  return __builtin_amdgcn_fmed3f(x, -1.0f, 1.0f);  // clip to [-c, c], c = MAX_WEIGHT = 1
}

// One block per batch element. 128 threads: thread t owns asset t.
// A-row (gamma-folded) lives in 128 VGPRs per thread; w is broadcast from LDS.
// __launch_bounds__(128, 1): min-waves/EU = 1 lifts the VGPR cap so the
// 128-register A-tile stays register-resident (R2: default budget spilled it
// to scratch at VGPR_Count=100 -> 39 GB of scratch reloads, 3.6 ms).
// Occupancy is grid-limited anyway (2048 blocks / 256 CUs = 8 blocks/CU).
__global__ __launch_bounds__(NA, 1) void markowitz_kernel(
    const float* __restrict__ rets,
    const float* __restrict__ covmat,
    const float* __restrict__ gamma,
    const float* __restrict__ alpha,
    float* __restrict__ out)
{
  const int b    = blockIdx.x;
  const int t    = threadIdx.x;
  const int lane = t & 63;
  const int wv   = t >> 6;  // wave 0 or 1

  __shared__ __align__(16) float ws[NA];   // current weights
  __shared__ __align__(16) float vs[NA];   // pre-projection vector for bisection
  __shared__ float pp[8];                  // [0..3]: w·Aw, w·w per wave; [4,5]: min; [6,7]: max
  __shared__ float tau_s;

  // ---- one-time load: A row t with gamma folded in (A = gamma * covmat) ----
  const float gm = gamma[b];
  const float4* Arow = reinterpret_cast<const float4*>(
      covmat + (size_t)b * NA * NA + (size_t)t * NA);
  float4 a[32];
#pragma unroll
  for (int k = 0; k < 32; ++k) {
    float4 q = Arow[k];
    a[k] = make_float4(q.x * gm, q.y * gm, q.z * gm, q.w * gm);
  }
  const float r_t = rets[b * NA + t];
  const float av  = fabsf(alpha[b]);

  float w_t = 1.0f / NA;
  ws[t] = w_t;
  __syncthreads();

#pragma unroll 1
  for (int it = 0; it < NIT; ++it) {
    // ---- 1. Aw[t] = A[t,:] · w  (A in regs, w broadcast from LDS) ----
    const float4* ws4 = reinterpret_cast<const float4*>(ws);
    float4 acc = make_float4(0.f, 0.f, 0.f, 0.f);
#pragma unroll
    for (int k = 0; k < 32; ++k) {
      float4 wk = ws4[k];  // uniform address -> single broadcast ds_read_b128
      acc.x = fmaf(a[k].x, wk.x, acc.x);
      acc.y = fmaf(a[k].y, wk.y, acc.y);
      acc.z = fmaf(a[k].z, wk.z, acc.z);
      acc.w = fmaf(a[k].w, wk.w, acc.w);
    }
    const float Aw = (acc.x + acc.y) + (acc.z + acc.w);

    // ---- 2. risk = sqrt(w·Aw + eps), nrm = sqrt(w·w + eps) ----
    float p1 = wave_sum64(w_t * Aw);
    float p2 = wave_sum64(w_t * w_t);
    if (lane == 63) { pp[wv * 2 + 0] = p1; pp[wv * 2 + 1] = p2; }
    __syncthreads();
    const float risk = sqrtf(pp[0] + pp[2] + EPSC);
    const float nrm  = sqrtf(pp[1] + pp[3] + EPSC);

    // ---- 3. gradient ascent step ----
    const float g_t = r_t - Aw / risk - av * (w_t / nrm);
    const float v_t = w_t + LRC * g_t;
    vs[t] = v_t;
    float mn = wave_min64(v_t);
    float mx = wave_max64(v_t);
    if (lane == 63) { pp[4 + wv] = mn; pp[6 + wv] = mx; }
    __syncthreads();

    // ---- 4. bisection for tau (wave 0 only; 2 elements per lane) ----
    if (wv == 0) {
      float v0 = vs[lane];
      float v1 = vs[lane + 64];
      float lo = fminf(pp[4], pp[5]) - 2.0f;  // min(v) - c - 1
      float hi = fmaxf(pp[6], pp[7]) + 1.0f;  // max(v) + c
#pragma unroll 1
      for (int r = 0; r < NBIS; ++r) {
        const float mid = 0.5f * (lo + hi);
        float s = clip1(v0 - mid) + clip1(v1 - mid);
        s = wave_sum64(s);
        const float stot = read_lane63(s);
        const bool big = stot > 1.0f;
        lo = big ? mid : lo;
        hi = big ? hi : mid;
      }
      if (lane == 0) tau_s = 0.5f * (lo + hi);
    }
    __syncthreads();

    // ---- 5. project: w = clip(v - tau, -c, c) ----
    const float tau = tau_s;
    w_t = clip1(v_t - tau);
    ws[t] = w_t;
    __syncthreads();
  }

  out[b * NA + t] = w_t;
}

extern "C" void kernel_launch(void* const* d_in, const int* in_sizes, int n_in,
                              void* d_out, int out_size, void* d_ws, size_t ws_size,
                              hipStream_t stream) {
  const float* rets   = (const float*)d_in[0];
  const float* covmat = (const float*)d_in[1];
  const float* gamma  = (const float*)d_in[2];
  const float* alpha  = (const float*)d_in[3];
  float* out = (float*)d_out;

  hipLaunchKernelGGL(markowitz_kernel, dim3(NBATCH), dim3(NA), 0, stream,
                     rets, covmat, gamma, alpha, out);
}

// Round 4
// 3271.674 us; speedup vs baseline: 1.1092x; 1.1080x over previous
//
#include <hip/hip_runtime.h>
#include <math.h>

#define NA      128
#define NBATCH  2048
#define NIT     300
#define NBIS    40
#define LRC     0.02f
#define EPSC    1e-8f

// ---- wave64 cross-lane reductions via DPP (VALU pipe, no LDS traffic) ----
// row_shr:n = 0x110+n ; row_bcast:15 = 0x142 ; row_bcast:31 = 0x143
// dpp_ctrl must be an ICE at the builtin call site -> template parameter.
template <int CTRL>
__device__ __forceinline__ float dpp_sum_step(float x) {
  int s = __builtin_amdgcn_update_dpp(0, __float_as_int(x), CTRL, 0xF, 0xF, true);
  return x + __int_as_float(s);
}
__device__ __forceinline__ float wave_sum64(float x) {
  x = dpp_sum_step<0x111>(x);
  x = dpp_sum_step<0x112>(x);
  x = dpp_sum_step<0x114>(x);
  x = dpp_sum_step<0x118>(x);
  x = dpp_sum_step<0x142>(x);
  x = dpp_sum_step<0x143>(x);
  return x;  // full-wave total lands in lane 63
}
template <int CTRL>
__device__ __forceinline__ float dpp_mov_self(float x) {
  // invalid/unwritten lanes keep old = x (identity for min/max)
  int s = __builtin_amdgcn_update_dpp(__float_as_int(x), __float_as_int(x), CTRL, 0xF, 0xF, false);
  return __int_as_float(s);
}
__device__ __forceinline__ float wave_min64(float x) {
  x = fminf(x, dpp_mov_self<0x111>(x));
  x = fminf(x, dpp_mov_self<0x112>(x));
  x = fminf(x, dpp_mov_self<0x114>(x));
  x = fminf(x, dpp_mov_self<0x118>(x));
  x = fminf(x, dpp_mov_self<0x142>(x));
  x = fminf(x, dpp_mov_self<0x143>(x));
  return x;  // min in lane 63
}
__device__ __forceinline__ float wave_max64(float x) {
  x = fmaxf(x, dpp_mov_self<0x111>(x));
  x = fmaxf(x, dpp_mov_self<0x112>(x));
  x = fmaxf(x, dpp_mov_self<0x114>(x));
  x = fmaxf(x, dpp_mov_self<0x118>(x));
  x = fmaxf(x, dpp_mov_self<0x142>(x));
  x = fmaxf(x, dpp_mov_self<0x143>(x));
  return x;  // max in lane 63
}
__device__ __forceinline__ float read_lane63(float x) {
  return __int_as_float(__builtin_amdgcn_readlane(__float_as_int(x), 63));
}
__device__ __forceinline__ float clip1(float x) {
  return __builtin_amdgcn_fmed3f(x, -1.0f, 1.0f);  // clip to [-c, c], c = MAX_WEIGHT = 1
}

// One block per batch element. 128 threads: thread t owns asset t.
// A-row (gamma-folded) lives in 128 VGPRs per thread; w is broadcast from LDS.
//
// amdgpu_waves_per_eu(1,2): the MAX bound is what raises the per-wave VGPR
// budget (512/2 = 256). R2/R3 evidence: with the default budget the allocator
// kept VGPR_Count=100 and rematerialized the A-tile loads inside the 300-iter
// loop (covmat is const __restrict__, so re-loading is legal) -> ~40 GB of
// L3-served re-reads, 3.6 ms, VALUBusy 34%. __launch_bounds__(128,1) was a
// no-op because its 2nd arg only sets the MIN waves/EU (already 1).
__global__
__attribute__((amdgpu_flat_work_group_size(128, 128)))
__attribute__((amdgpu_waves_per_eu(1, 2)))
void markowitz_kernel(
    const float* __restrict__ rets,
    const float* __restrict__ covmat,
    const float* __restrict__ gamma,
    const float* __restrict__ alpha,
    float* __restrict__ out)
{
  const int b    = blockIdx.x;
  const int t    = threadIdx.x;
  const int lane = t & 63;
  const int wv   = t >> 6;  // wave 0 or 1

  __shared__ __align__(16) float ws[NA];   // current weights
  __shared__ __align__(16) float vs[NA];   // pre-projection vector for bisection
  __shared__ float pp[8];                  // [0..3]: w·Aw, w·w per wave; [4,5]: min; [6,7]: max
  __shared__ float tau_s;

  // ---- one-time load: A row t with gamma folded in (A = gamma * covmat) ----
  const float gm = gamma[b];
  const float4* Arow = reinterpret_cast<const float4*>(
      covmat + (size_t)b * NA * NA + (size_t)t * NA);
  float4 a[32];
#pragma unroll
  for (int k = 0; k < 32; ++k) {
    float4 q = Arow[k];
    a[k] = make_float4(q.x * gm, q.y * gm, q.z * gm, q.w * gm);
  }
  const float r_t = rets[b * NA + t];
  const float av  = fabsf(alpha[b]);

  float w_t = 1.0f / NA;
  ws[t] = w_t;
  __syncthreads();

#pragma unroll 1
  for (int it = 0; it < NIT; ++it) {
    // ---- 1. Aw[t] = A[t,:] · w  (A in regs, w broadcast from LDS) ----
    const float4* ws4 = reinterpret_cast<const float4*>(ws);
    float4 acc = make_float4(0.f, 0.f, 0.f, 0.f);
#pragma unroll
    for (int k = 0; k < 32; ++k) {
      float4 wk = ws4[k];  // uniform address -> single broadcast ds_read_b128
      acc.x = fmaf(a[k].x, wk.x, acc.x);
      acc.y = fmaf(a[k].y, wk.y, acc.y);
      acc.z = fmaf(a[k].z, wk.z, acc.z);
      acc.w = fmaf(a[k].w, wk.w, acc.w);
    }
    const float Aw = (acc.x + acc.y) + (acc.z + acc.w);

    // ---- 2. risk = sqrt(w·Aw + eps), nrm = sqrt(w·w + eps) ----
    float p1 = wave_sum64(w_t * Aw);
    float p2 = wave_sum64(w_t * w_t);
    if (lane == 63) { pp[wv * 2 + 0] = p1; pp[wv * 2 + 1] = p2; }
    __syncthreads();
    const float risk = sqrtf(pp[0] + pp[2] + EPSC);
    const float nrm  = sqrtf(pp[1] + pp[3] + EPSC);

    // ---- 3. gradient ascent step ----
    const float g_t = r_t - Aw / risk - av * (w_t / nrm);
    const float v_t = w_t + LRC * g_t;
    vs[t] = v_t;
    float mn = wave_min64(v_t);
    float mx = wave_max64(v_t);
    if (lane == 63) { pp[4 + wv] = mn; pp[6 + wv] = mx; }
    __syncthreads();

    // ---- 4. bisection for tau (wave 0 only; 2 elements per lane) ----
    if (wv == 0) {
      float v0 = vs[lane];
      float v1 = vs[lane + 64];
      float lo = fminf(pp[4], pp[5]) - 2.0f;  // min(v) - c - 1
      float hi = fmaxf(pp[6], pp[7]) + 1.0f;  // max(v) + c
#pragma unroll 1
      for (int r = 0; r < NBIS; ++r) {
        const float mid = 0.5f * (lo + hi);
        float s = clip1(v0 - mid) + clip1(v1 - mid);
        s = wave_sum64(s);
        const float stot = read_lane63(s);
        const bool big = stot > 1.0f;
        lo = big ? mid : lo;
        hi = big ? hi : mid;
      }
      if (lane == 0) tau_s = 0.5f * (lo + hi);
    }
    __syncthreads();

    // ---- 5. project: w = clip(v - tau, -c, c) ----
    const float tau = tau_s;
    w_t = clip1(v_t - tau);
    ws[t] = w_t;
    __syncthreads();
  }

  out[b * NA + t] = w_t;
}

extern "C" void kernel_launch(void* const* d_in, const int* in_sizes, int n_in,
                              void* d_out, int out_size, void* d_ws, size_t ws_size,
                              hipStream_t stream) {
  const float* rets   = (const float*)d_in[0];
  const float* covmat = (const float*)d_in[1];
  const float* gamma  = (const float*)d_in[2];
  const float* alpha  = (const float*)d_in[3];
  float* out = (float*)d_out;

  hipLaunchKernelGGL(markowitz_kernel, dim3(NBATCH), dim3(NA), 0, stream,
                     rets, covmat, gamma, alpha, out);
}